// Round 2
// baseline (593.378 us; speedup 1.0000x reference)
//
#include <hip/hip_runtime.h>
#include <math.h>

#define Bn 512
#define Tn 1024
#define Nn 64
#define LOG2E_F 1.44269504088896340736f
#define LN2_F   0.69314718055994530942f

// ---------------------------------------------------------------------------
// Kernel 1: unary + binary scores -> out[b]
// unary  = sum_{t<L} inputs[b,t,tag[t]]
// binary = sum_{1<=t<L} trans[tag[t-1], tag[t]]
// ---------------------------------------------------------------------------
__global__ __launch_bounds__(256) void crf_scores(
    const float* __restrict__ inputs, const float* __restrict__ trans,
    const int* __restrict__ tags, const int* __restrict__ lens,
    float* __restrict__ out)
{
    const int b = blockIdx.x;
    const int L = lens[b];
    const int* tagb = tags + b * Tn;
    const float* inb = inputs + (size_t)b * Tn * Nn;

    float acc = 0.f;
    for (int t = threadIdx.x; t < Tn; t += 256) {
        if (t < L) {
            int tg = tagb[t];
            acc += inb[t * Nn + tg];
            if (t >= 1) acc += trans[tagb[t - 1] * Nn + tg];
        }
    }
    // wave reduce then cross-wave via LDS
    #pragma unroll
    for (int o = 32; o > 0; o >>= 1) acc += __shfl_xor(acc, o);
    __shared__ float red[4];
    if ((threadIdx.x & 63) == 0) red[threadIdx.x >> 6] = acc;
    __syncthreads();
    if (threadIdx.x == 0) out[b] = (red[0] + red[1]) + (red[2] + red[3]);
}

// ---------------------------------------------------------------------------
// Kernel 2: forward/backward halves of the linear recursion in exp-space.
//   q_t = diag(e^{x_t}/64) applied to (q_{t-1} . E),  E = exp(trans)
// FULL=true: one block per batch runs the whole chain and writes out directly.
// FULL=false: blocks [0,512) run forward halves, [512,1024) backward halves;
//             results (renormalized vector + log-base) go to workspace.
// ---------------------------------------------------------------------------
template <bool FULL>
__global__ __launch_bounds__(64) void crf_fwdbwd(
    const float* __restrict__ inputs, const float* __restrict__ trans,
    const int* __restrict__ lens, float* __restrict__ ws,
    float* __restrict__ out)
{
    const int j = threadIdx.x;
    const bool bwd = (!FULL) && (blockIdx.x >= Bn);
    const int b = bwd ? (blockIdx.x - Bn) : blockIdx.x;
    const int L = lens[b];
    const float* inb = inputs + (size_t)b * Tn * Nn;

    // stage trans in LDS (stride 68 keeps float4 alignment; setup-only cost)
    __shared__ float trsh[64 * 68];
    __shared__ __align__(16) float qsh[64];

    for (int i = 0; i < 64; ++i) trsh[i * 68 + j] = trans[i * 64 + j];
    __syncthreads();

    // E in registers: forward lane j holds column j (E[i][j]);
    // backward lane j holds row j (E[j][i]).
    float E[64];
    if (!bwd) {
        #pragma unroll
        for (int i = 0; i < 64; ++i) E[i] = exp2f(trsh[i * 68 + j] * LOG2E_F);
    } else {
        #pragma unroll
        for (int i = 0; i < 64; ++i) E[i] = exp2f(trsh[j * 68 + i] * LOG2E_F);
    }
    __syncthreads();

    float q, base;
    int t0, dir, n;
    const int tf = L >> 1;           // forward covers t in [1,tf], backward (tf, L-1]
    if (!bwd) {
        float x0 = inb[j];
        float m = x0;
        #pragma unroll
        for (int o = 32; o > 0; o >>= 1) m = fmaxf(m, __shfl_xor(m, o));
        q = exp2f((x0 - m) * LOG2E_F);
        base = m;
        t0 = 1; dir = 1;
        n = FULL ? (L - 1) : tf;
    } else {
        q = 1.f; base = 0.f;
        t0 = L - 1; dir = -1;
        n = (L - 1) - tf;
    }

    int t = t0;
    float x = (n > 0) ? inb[t * Nn + j] : 0.f;
    for (int k = 0; k < n; ++k) {
        float xn = 0.f;
        if (k + 1 < n) xn = inb[(t + dir) * Nn + j];      // prefetch next row
        float ex = exp2f(fmaf(x, LOG2E_F, -6.0f));        // e^x / 64 (off critical path)

        float v = bwd ? ex * q : q;                       // value to broadcast
        qsh[j] = v;
        __syncthreads();                                  // single wave: acts as LDS fence

        float s0 = 0.f, s1 = 0.f, s2 = 0.f, s3 = 0.f;
        #pragma unroll
        for (int i = 0; i < 64; i += 4) {
            float4 qq = *(const float4*)(qsh + i);        // broadcast b128 reads
            s0 = fmaf(qq.x, E[i],     s0);
            s1 = fmaf(qq.y, E[i + 1], s1);
            s2 = fmaf(qq.z, E[i + 2], s2);
            s3 = fmaf(qq.w, E[i + 3], s3);
        }
        float s = (s0 + s1) + (s2 + s3);
        q = bwd ? s : ex * s;

        if ((k & 7) == 7) {                               // periodic renorm (range safety)
            float m = q;
            #pragma unroll
            for (int o = 32; o > 0; o >>= 1) m = fmaxf(m, __shfl_xor(m, o));
            q *= (1.0f / m);
            base += __logf(m);
        }
        x = xn; t += dir;
    }

    // final renorm + account for the per-step 1/64 scaling
    {
        float m = q;
        #pragma unroll
        for (int o = 32; o > 0; o >>= 1) m = fmaxf(m, __shfl_xor(m, o));
        q *= (1.0f / m);
        base += __logf(m) + LN2_F * 6.0f * (float)n;
    }

    if (FULL) {
        float ssum = q;
        #pragma unroll
        for (int o = 32; o > 0; o >>= 1) ssum += __shfl_xor(ssum, o);
        if (j == 0) out[b] -= (base + __logf(ssum));
    } else {
        float* fvec = ws;
        float* gvec = ws + Bn * 64;
        float* fb   = ws + 2 * Bn * 64;
        float* gb   = fb + Bn;
        if (!bwd) { fvec[b * 64 + j] = q; if (j == 0) fb[b] = base; }
        else      { gvec[b * 64 + j] = q; if (j == 0) gb[b] = base; }
    }
}

// ---------------------------------------------------------------------------
// Kernel 3: combine halves: logZ = log(f . g) + fbase + gbase; out[b] -= logZ
// ---------------------------------------------------------------------------
__global__ __launch_bounds__(64) void crf_combine(
    const float* __restrict__ ws, float* __restrict__ out)
{
    const int b = blockIdx.x;
    const int j = threadIdx.x;
    const float* fvec = ws;
    const float* gvec = ws + Bn * 64;
    const float* fb   = ws + 2 * Bn * 64;
    const float* gb   = fb + Bn;

    float p = fvec[b * 64 + j] * gvec[b * 64 + j];
    #pragma unroll
    for (int o = 32; o > 0; o >>= 1) p += __shfl_xor(p, o);
    if (j == 0) out[b] -= (__logf(p) + fb[b] + gb[b]);
}

extern "C" void kernel_launch(void* const* d_in, const int* in_sizes, int n_in,
                              void* d_out, int out_size, void* d_ws, size_t ws_size,
                              hipStream_t stream) {
    const float* inputs = (const float*)d_in[0];
    const float* trans  = (const float*)d_in[1];
    const int*   tags   = (const int*)d_in[2];
    const int*   lens   = (const int*)d_in[3];
    float* out = (float*)d_out;
    float* ws  = (float*)d_ws;

    crf_scores<<<Bn, 256, 0, stream>>>(inputs, trans, tags, lens, out);

    const size_t need = (size_t)(2 * Bn * 64 + 2 * Bn) * sizeof(float);
    if (ws_size >= need) {
        crf_fwdbwd<false><<<2 * Bn, 64, 0, stream>>>(inputs, trans, lens, ws, out);
        crf_combine<<<Bn, 64, 0, stream>>>(ws, out);
    } else {
        // workspace too small: single-direction fallback (slower, no ws needed)
        crf_fwdbwd<true><<<Bn, 64, 0, stream>>>(inputs, trans, lens, ws, out);
    }
}

// Round 4
// 393.729 us; speedup vs baseline: 1.5071x; 1.5071x over previous
//
#include <hip/hip_runtime.h>
#include <math.h>

#define Bn 512
#define Tn 1024
#define Nn 64
#define LOG2E_F 1.44269504088896340736f
#define LN2_F   0.69314718055994530942f

__device__ __forceinline__ float bcast_lane(float v, int lane) {
    return __int_as_float(__builtin_amdgcn_readlane(__float_as_int(v), lane));
}

// ---------------------------------------------------------------------------
// Kernel 1: unary + binary scores -> out[b]
// One block per batch, one thread per timestep (16 waves -> latency hiding).
// ---------------------------------------------------------------------------
__global__ __launch_bounds__(1024) void crf_scores(
    const float* __restrict__ inputs, const float* __restrict__ trans,
    const int* __restrict__ tags, const int* __restrict__ lens,
    float* __restrict__ out)
{
    const int b = blockIdx.x;
    const int t = threadIdx.x;          // 0..1023 == Tn
    __shared__ int tsh[Tn];
    __shared__ float red[16];

    const int L = lens[b];
    tsh[t] = tags[b * Tn + t];
    __syncthreads();

    float acc = 0.f;
    if (t < L) {
        int tg = tsh[t];
        acc = inputs[(size_t)b * Tn * Nn + t * Nn + tg];
        if (t >= 1) acc += trans[tsh[t - 1] * Nn + tg];
    }
    #pragma unroll
    for (int o = 32; o > 0; o >>= 1) acc += __shfl_xor(acc, o);
    if ((t & 63) == 0) red[t >> 6] = acc;
    __syncthreads();
    if (t == 0) {
        float s = 0.f;
        #pragma unroll
        for (int i = 0; i < 16; ++i) s += red[i];
        out[b] = s;
    }
}

// ---------------------------------------------------------------------------
// Kernel 2: forward/backward halves of the linear recursion in exp-space.
//   q_t = diag(e^{x_t}/64) applied to (q_{t-1} . E),  E = exp(trans)
// Broadcast of q across lanes is done with v_readlane (no LDS, no barrier,
// no vmcnt drain in the loop) so the 4-deep global prefetch stays async.
// ---------------------------------------------------------------------------
template <bool FULL>
__global__ __launch_bounds__(64) void crf_fwdbwd(
    const float* __restrict__ inputs, const float* __restrict__ trans,
    const int* __restrict__ lens, float* __restrict__ ws,
    float* __restrict__ out)
{
    const int j = threadIdx.x;
    const bool bwd = (!FULL) && (blockIdx.x >= Bn);
    const int b = bwd ? (blockIdx.x - Bn) : blockIdx.x;
    const int L = lens[b];
    const float* inb = inputs + (size_t)b * Tn * Nn;

    // stage trans in LDS once (stride 68: float4-aligned, conflict-free)
    __shared__ float trsh[64 * 68];
    for (int i = 0; i < 64; ++i) trsh[i * 68 + j] = trans[i * 64 + j];
    __syncthreads();

    // E in registers: forward lane j holds column j (E[i][j]);
    // backward lane j holds row j (E[j][i]).
    float E[64];
    if (!bwd) {
        #pragma unroll
        for (int i = 0; i < 64; ++i) E[i] = exp2f(trsh[i * 68 + j] * LOG2E_F);
    } else {
        #pragma unroll
        for (int i = 0; i < 64; ++i) E[i] = exp2f(trsh[j * 68 + i] * LOG2E_F);
    }

    float q, base;
    int t0, dir, n;
    const int tf = L >> 1;           // forward covers t in [1,tf], backward (tf, L-1]
    if (!bwd) {
        float x0 = inb[j];
        float m = x0;
        #pragma unroll
        for (int o = 32; o > 0; o >>= 1) m = fmaxf(m, __shfl_xor(m, o));
        q = exp2f((x0 - m) * LOG2E_F);
        base = m;
        t0 = 1; dir = 1;
        n = FULL ? (L - 1) : tf;
    } else {
        q = 1.f; base = 0.f;
        t0 = L - 1; dir = -1;
        n = (L - 1) - tf;
    }

    // 4-deep register prefetch pipeline for x rows
    float xp[4];
    #pragma unroll
    for (int d = 0; d < 4; ++d) xp[d] = (d < n) ? inb[(t0 + d * dir) * Nn + j] : 0.f;

    int t = t0;
    float ex = exp2f(fmaf(xp[0], LOG2E_F, -6.0f));  // e^x / 64, one step ahead
    for (int k = 0; k < n; ++k) {
        const float v = bwd ? ex * q : q;           // value to broadcast

        // s_j = sum_i v_i * E[i]   via readlane broadcast (no LDS, no fence)
        float s0 = 0.f, s1 = 0.f, s2 = 0.f, s3 = 0.f;
        #pragma unroll
        for (int i = 0; i < 64; i += 4) {
            float a0 = bcast_lane(v, i);
            float a1 = bcast_lane(v, i + 1);
            float a2 = bcast_lane(v, i + 2);
            float a3 = bcast_lane(v, i + 3);
            s0 = fmaf(a0, E[i],     s0);
            s1 = fmaf(a1, E[i + 1], s1);
            s2 = fmaf(a2, E[i + 2], s2);
            s3 = fmaf(a3, E[i + 3], s3);
        }

        // rotate prefetch pipeline; compute next step's exp off critical path
        xp[0] = xp[1]; xp[1] = xp[2]; xp[2] = xp[3];
        if (k + 4 < n) xp[3] = inb[(t + 4 * dir) * Nn + j];
        float exn = exp2f(fmaf(xp[0], LOG2E_F, -6.0f));

        float s = (s0 + s1) + (s2 + s3);
        q = bwd ? s : ex * s;

        if ((k & 7) == 7) {                          // periodic renorm (range safety)
            float m = q;
            #pragma unroll
            for (int o = 32; o > 0; o >>= 1) m = fmaxf(m, __shfl_xor(m, o));
            q *= (1.0f / m);
            base += __logf(m);
        }
        ex = exn; t += dir;
    }

    // final renorm + account for the per-step 1/64 scaling
    {
        float m = q;
        #pragma unroll
        for (int o = 32; o > 0; o >>= 1) m = fmaxf(m, __shfl_xor(m, o));
        q *= (1.0f / m);
        base += __logf(m) + LN2_F * 6.0f * (float)n;
    }

    if (FULL) {
        float ssum = q;
        #pragma unroll
        for (int o = 32; o > 0; o >>= 1) ssum += __shfl_xor(ssum, o);
        if (j == 0) out[b] -= (base + __logf(ssum));
    } else {
        float* fvec = ws;
        float* gvec = ws + Bn * 64;
        float* fb   = ws + 2 * Bn * 64;
        float* gb   = fb + Bn;
        if (!bwd) { fvec[b * 64 + j] = q; if (j == 0) fb[b] = base; }
        else      { gvec[b * 64 + j] = q; if (j == 0) gb[b] = base; }
    }
}

// ---------------------------------------------------------------------------
// Kernel 3: combine halves: logZ = log(f . g) + fbase + gbase; out[b] -= logZ
// ---------------------------------------------------------------------------
__global__ __launch_bounds__(64) void crf_combine(
    const float* __restrict__ ws, float* __restrict__ out)
{
    const int b = blockIdx.x;
    const int j = threadIdx.x;
    const float* fvec = ws;
    const float* gvec = ws + Bn * 64;
    const float* fb   = ws + 2 * Bn * 64;
    const float* gb   = fb + Bn;

    float p = fvec[b * 64 + j] * gvec[b * 64 + j];
    #pragma unroll
    for (int o = 32; o > 0; o >>= 1) p += __shfl_xor(p, o);
    if (j == 0) out[b] -= (__logf(p) + fb[b] + gb[b]);
}

extern "C" void kernel_launch(void* const* d_in, const int* in_sizes, int n_in,
                              void* d_out, int out_size, void* d_ws, size_t ws_size,
                              hipStream_t stream) {
    const float* inputs = (const float*)d_in[0];
    const float* trans  = (const float*)d_in[1];
    const int*   tags   = (const int*)d_in[2];
    const int*   lens   = (const int*)d_in[3];
    float* out = (float*)d_out;
    float* ws  = (float*)d_ws;

    crf_scores<<<Bn, 1024, 0, stream>>>(inputs, trans, tags, lens, out);

    const size_t need = (size_t)(2 * Bn * 64 + 2 * Bn) * sizeof(float);
    if (ws_size >= need) {
        crf_fwdbwd<false><<<2 * Bn, 64, 0, stream>>>(inputs, trans, lens, ws, out);
        crf_combine<<<Bn, 64, 0, stream>>>(ws, out);
    } else {
        // workspace too small: single-direction fallback (slower, no ws needed)
        crf_fwdbwd<true><<<Bn, 64, 0, stream>>>(inputs, trans, lens, ws, out);
    }
}

// Round 5
// 387.665 us; speedup vs baseline: 1.5306x; 1.0156x over previous
//
#include <hip/hip_runtime.h>
#include <math.h>

#define Bn 512
#define Tn 1024
#define Nn 64
#define LOG2E_F 1.44269504088896340736f
#define LN2_F   0.69314718055994530942f

__device__ __forceinline__ float bcast_lane(float v, int lane) {
    return __int_as_float(__builtin_amdgcn_readlane(__float_as_int(v), lane));
}
__device__ __forceinline__ float wave_max(float v) {
    #pragma unroll
    for (int o = 32; o > 0; o >>= 1) v = fmaxf(v, __shfl_xor(v, o));
    return v;
}
__device__ __forceinline__ float wave_sum(float v) {
    #pragma unroll
    for (int o = 32; o > 0; o >>= 1) v += __shfl_xor(v, o);
    return v;
}

// ---------------------------------------------------------------------------
// Kernel 1: unary + binary scores -> out[b]
// ---------------------------------------------------------------------------
__global__ __launch_bounds__(256) void crf_scores(
    const float* __restrict__ inputs, const float* __restrict__ trans,
    const int* __restrict__ tags, const int* __restrict__ lens,
    float* __restrict__ out)
{
    const int b = blockIdx.x;
    const int L = lens[b];
    const int* tagb = tags + b * Tn;
    const float* inb = inputs + (size_t)b * Tn * Nn;

    float acc = 0.f;
    for (int t = threadIdx.x; t < L; t += 256) {
        int tg = tagb[t];
        acc += inb[t * Nn + tg];
        if (t >= 1) acc += trans[tagb[t - 1] * Nn + tg];
    }
    acc = wave_sum(acc);
    __shared__ float red[4];
    if ((threadIdx.x & 63) == 0) red[threadIdx.x >> 6] = acc;
    __syncthreads();
    if (threadIdx.x == 0) out[b] = (red[0] + red[1]) + (red[2] + red[3]);
}

// ---------------------------------------------------------------------------
// Kernel 2: forward/backward halves of the linear recursion in exp-space.
//   fwd: q' = e^{x_t}/64 (elementwise, lane j) * sum_i q_i E[i][j]
//   bwd: q' = sum_i (e^{x_t}/64 * q)_i E[j][i]   (lane j holds row j)
// Broadcast via v_readlane: no LDS, no barrier, no vmcnt drain in the loop.
// __launch_bounds__(64,1): 1 wave/EU is structural here; give the register
// allocator the full budget so E[64] stays in VGPRs (68-VGPR cap caused
// spill-reload in the loop in R4 -> ~800 stall cyc/step).
// ---------------------------------------------------------------------------

// s_j = sum_i v_i * E[i]  (v broadcast across lanes via readlane)
#define DOT64(vv, dst) do {                                        \
    float _s0 = 0.f, _s1 = 0.f, _s2 = 0.f, _s3 = 0.f;             \
    _Pragma("unroll")                                              \
    for (int _i = 0; _i < 64; _i += 4) {                           \
        _s0 = fmaf(bcast_lane((vv), _i    ), E[_i    ], _s0);      \
        _s1 = fmaf(bcast_lane((vv), _i + 1), E[_i + 1], _s1);      \
        _s2 = fmaf(bcast_lane((vv), _i + 2), E[_i + 2], _s2);      \
        _s3 = fmaf(bcast_lane((vv), _i + 3), E[_i + 3], _s3);      \
    }                                                              \
    (dst) = (_s0 + _s1) + (_s2 + _s3);                             \
} while (0)

// one recursion step; rotates the 4-deep prefetch pipeline
#define STEP(BWDV, kk) do {                                        \
    float _s;                                                      \
    if (BWDV) { float _v = ex * q; DOT64(_v, _s); }                \
    else      { DOT64(q, _s); }                                    \
    xp[0] = xp[1]; xp[1] = xp[2]; xp[2] = xp[3];                   \
    if ((kk) + 4 < n) xp[3] = inb[(t + 4 * dir) * Nn + j];         \
    float _exn = exp2f(fmaf(xp[0], LOG2E_F, -6.0f));               \
    q = (BWDV) ? _s : ex * _s;                                     \
    ex = _exn; t += dir;                                           \
} while (0)

#define RENORM() do {                                              \
    float _m = wave_max(q);                                        \
    q *= (1.0f / _m);                                              \
    base += __logf(_m);                                            \
} while (0)

template <bool FULL>
__global__ __launch_bounds__(64, 1) void crf_fwdbwd(
    const float* __restrict__ inputs, const float* __restrict__ trans,
    const int* __restrict__ lens, float* __restrict__ ws,
    float* __restrict__ out)
{
    const int j = threadIdx.x;
    const bool bwd = (!FULL) && (blockIdx.x >= Bn);
    const int b = bwd ? (blockIdx.x - Bn) : blockIdx.x;
    const int L = lens[b];
    const float* inb = inputs + (size_t)b * Tn * Nn;

    // E in registers: fwd lane j holds column j (E[i][j]) -- coalesced direct;
    // bwd lane j holds row j (E[j][i]) -- transpose via LDS (setup only).
    float E[64];
    __shared__ float trsh[64 * 65];
    if (!bwd) {
        #pragma unroll
        for (int i = 0; i < 64; ++i) E[i] = exp2f(trans[i * 64 + j] * LOG2E_F);
    } else {
        #pragma unroll
        for (int i = 0; i < 64; ++i) trsh[i * 65 + j] = trans[i * 64 + j];
        __syncthreads();
        #pragma unroll
        for (int i = 0; i < 64; ++i) E[i] = exp2f(trsh[j * 65 + i] * LOG2E_F);
    }

    float q, base;
    int t0, dir, n;
    const int tf = L >> 1;           // forward covers t in [1,tf], backward (tf, L-1]
    if (!bwd) {
        float x0 = inb[j];
        float m = wave_max(x0);
        q = exp2f((x0 - m) * LOG2E_F);
        base = m;
        t0 = 1; dir = 1;
        n = FULL ? (L - 1) : tf;
    } else {
        q = 1.f; base = 0.f;
        t0 = L - 1; dir = -1;
        n = (L - 1) - tf;
    }

    // 4-deep register prefetch pipeline for x rows
    float xp[4];
    #pragma unroll
    for (int d = 0; d < 4; ++d) xp[d] = (d < n) ? inb[(t0 + d * dir) * Nn + j] : 0.f;

    int t = t0;
    float ex = exp2f(fmaf(xp[0], LOG2E_F, -6.0f));  // e^x / 64, one step ahead

    int k = 0;
    if (!bwd) {
        while (k + 8 <= n) {
            #pragma unroll
            for (int u = 0; u < 8; ++u) STEP(false, k + u);
            k += 8;
            RENORM();
        }
        while (k < n) { STEP(false, k); ++k; }
    } else {
        while (k + 8 <= n) {
            #pragma unroll
            for (int u = 0; u < 8; ++u) STEP(true, k + u);
            k += 8;
            RENORM();
        }
        while (k < n) { STEP(true, k); ++k; }
    }

    // final renorm + account for the per-step 1/64 scaling
    {
        float m = wave_max(q);
        q *= (1.0f / m);
        base += __logf(m) + LN2_F * 6.0f * (float)n;
    }

    if (FULL) {
        float ssum = wave_sum(q);
        if (j == 0) out[b] -= (base + __logf(ssum));
    } else {
        float* fvec = ws;
        float* gvec = ws + Bn * 64;
        float* fb   = ws + 2 * Bn * 64;
        float* gb   = fb + Bn;
        if (!bwd) { fvec[b * 64 + j] = q; if (j == 0) fb[b] = base; }
        else      { gvec[b * 64 + j] = q; if (j == 0) gb[b] = base; }
    }
}

// ---------------------------------------------------------------------------
// Kernel 3: combine halves: logZ = log(f . g) + fbase + gbase; out[b] -= logZ
// ---------------------------------------------------------------------------
__global__ __launch_bounds__(64, 1) void crf_combine(
    const float* __restrict__ ws, float* __restrict__ out)
{
    const int b = blockIdx.x;
    const int j = threadIdx.x;
    const float* fvec = ws;
    const float* gvec = ws + Bn * 64;
    const float* fb   = ws + 2 * Bn * 64;
    const float* gb   = fb + Bn;

    float p = wave_sum(fvec[b * 64 + j] * gvec[b * 64 + j]);
    if (j == 0) out[b] -= (__logf(p) + fb[b] + gb[b]);
}

extern "C" void kernel_launch(void* const* d_in, const int* in_sizes, int n_in,
                              void* d_out, int out_size, void* d_ws, size_t ws_size,
                              hipStream_t stream) {
    const float* inputs = (const float*)d_in[0];
    const float* trans  = (const float*)d_in[1];
    const int*   tags   = (const int*)d_in[2];
    const int*   lens   = (const int*)d_in[3];
    float* out = (float*)d_out;
    float* ws  = (float*)d_ws;

    crf_scores<<<Bn, 256, 0, stream>>>(inputs, trans, tags, lens, out);

    const size_t need = (size_t)(2 * Bn * 64 + 2 * Bn) * sizeof(float);
    if (ws_size >= need) {
        crf_fwdbwd<false><<<2 * Bn, 64, 0, stream>>>(inputs, trans, lens, ws, out);
        crf_combine<<<Bn, 64, 0, stream>>>(ws, out);
    } else {
        // workspace too small: single-direction fallback (slower, no ws needed)
        crf_fwdbwd<true><<<Bn, 64, 0, stream>>>(inputs, trans, lens, ws, out);
    }
}